// Round 3
// baseline (5013.375 us; speedup 1.0000x reference)
//
#include <hip/hip_runtime.h>

#define HH 512
#define WW 512
#define HWSZ (HH * WW)
#define NP 2      // points per thread. NP=4 spilled at per-layer fences (R1);
                  // NP=2 with per-layer fences ALSO spilled (R2: scheduler
                  // hoists all 64 weight float4 of a 16x16 layer = 256 VGPR).
                  // Fix: fence per jg-group (17 float4 window) + VGPR budget.
#define BLK 256

// LDS layout (float offsets). All float4-group bases are 16B-aligned.
#define O_W1 0      // 7x16
#define O_B1 112    // 16
#define O_W2 128    // 16x16
#define O_B2 384    // 16
#define O_W3 400    // 16x16
#define O_B3 656    // 16
#define O_W4 672    // 16x16
#define O_B4 928    // 16
#define O_W5 944    // 16x4 (padded from 16x3)
#define O_B5 1008   // 4 (padded from 3)
#define SW_TOT 1012

// Scheduler fence: NO instruction may be moved across (mask 0). Placed
// around each jg-group so at most 17 ds_read_b128 (68 floats) of weights can
// be hoisted into flight at once. R2 proved per-LAYER fences are too coarse:
// the scheduler hoisted a whole 16x16 layer (256 floats) -> VGPR=256 -> spill.
#define JG_FENCE() __builtin_amdgcn_sched_barrier(0)

// ---------------------------------------------------------------------------
// Pre-pass: transpose featuremap (C,H,W) -> (H,W,C): one bilinear corner = one
// aligned float4 load.
// ---------------------------------------------------------------------------
__global__ void fm_transpose(const float* __restrict__ fm, float* __restrict__ fmT) {
    int i = blockIdx.x * blockDim.x + threadIdx.x;
    if (i < HWSZ) {
        float4 v;
        v.x = fm[i];
        v.y = fm[HWSZ + i];
        v.z = fm[2 * HWSZ + i];
        v.w = fm[3 * HWSZ + i];
        reinterpret_cast<float4*>(fmT)[i] = v;
    }
}

// ---------------------------------------------------------------------------
// Fused grid_sample + MLP, NP=2 points/thread.
// Weights staged in LDS, read via uniform-address ds_read_b128 (broadcast,
// conflict-free). Each weight float4 read feeds 4*NP=8 FMAs, halving the
// per-CU LDS broadcast-read occupancy (~110us -> ~55us per full pass) that
// was co-bottlenecking round-0, and giving the FMA stream 2 independent
// chains to hide ds_read latency.
// __launch_bounds__(BLK, 3): allocator budget ~168 VGPR (3 waves/EU) so the
// pressure-aware scheduler plans within it instead of ballooning to 256.
// ---------------------------------------------------------------------------
template <bool TR>
__global__ __launch_bounds__(BLK, 3) void mlp_fused(
    const float* __restrict__ x, const float* __restrict__ fm,
    const float* __restrict__ W1, const float* __restrict__ b1,
    const float* __restrict__ W2, const float* __restrict__ b2,
    const float* __restrict__ W3, const float* __restrict__ b3,
    const float* __restrict__ W4, const float* __restrict__ b4,
    const float* __restrict__ W5, const float* __restrict__ b5,
    float* __restrict__ out, int n)
{
    __shared__ __align__(16) float sW[SW_TOT];
    const int tid = threadIdx.x;

    // ---- stage weights into LDS (one pass; 256 threads) ----
    if (tid < 112) sW[O_W1 + tid] = W1[tid];
    if (tid < 16) {
        sW[O_B1 + tid] = b1[tid];
        sW[O_B2 + tid] = b2[tid];
        sW[O_B3 + tid] = b3[tid];
        sW[O_B4 + tid] = b4[tid];
    }
    {   // W2/W3/W4: exactly one element per thread
        sW[O_W2 + tid] = W2[tid];
        sW[O_W3 + tid] = W3[tid];
        sW[O_W4 + tid] = W4[tid];
    }
    if (tid < 64) {  // W5 padded 16x3 -> 16x4
        int r = tid >> 2, c = tid & 3;
        sW[O_W5 + tid] = (c < 3) ? W5[r * 3 + c] : 0.f;
    }
    if (tid < 4) sW[O_B5 + tid] = (tid < 3) ? b5[tid] : 0.f;
    __syncthreads();

    const int base = blockIdx.x * (BLK * NP) + tid;

    // ---- per-point: load coords, bilinear sample (identical arithmetic to
    //      reference), border clamp ----
    float in[NP][7];
    bool ok[NP];

#pragma unroll
    for (int j = 0; j < NP; ++j) {
        int i = base + j * BLK;
        ok[j] = (i < n);
        int ii = ok[j] ? i : 0;  // clamp OOB lanes to a valid point; store is predicated

        float p0 = x[3 * ii], p1 = x[3 * ii + 1], p2 = x[3 * ii + 2];

        float gx = p0 * 2.f - 1.f;
        float gy = p1 * 2.f - 1.f;
        float fx = ((gx + 1.f) * (float)WW - 1.f) * 0.5f;
        float fy = ((gy + 1.f) * (float)HH - 1.f) * 0.5f;
        fx = fminf(fmaxf(fx, 0.f), (float)(WW - 1));
        fy = fminf(fmaxf(fy, 0.f), (float)(HH - 1));
        float x0f = floorf(fx), y0f = floorf(fy);
        float wx = fx - x0f, wy = fy - y0f;
        int ix0 = (int)x0f, iy0 = (int)y0f;
        int ix1 = min(ix0 + 1, WW - 1);
        int iy1 = min(iy0 + 1, HH - 1);
        float w00 = (1.f - wy) * (1.f - wx);
        float w01 = (1.f - wy) * wx;
        float w10 = wy * (1.f - wx);
        float w11 = wy * wx;

        float feat[4];
        if (TR) {
            const float4* fmT = reinterpret_cast<const float4*>(fm);
            float4 v00 = fmT[iy0 * WW + ix0];
            float4 v01 = fmT[iy0 * WW + ix1];
            float4 v10 = fmT[iy1 * WW + ix0];
            float4 v11 = fmT[iy1 * WW + ix1];
            feat[0] = v00.x * w00 + v01.x * w01 + v10.x * w10 + v11.x * w11;
            feat[1] = v00.y * w00 + v01.y * w01 + v10.y * w10 + v11.y * w11;
            feat[2] = v00.z * w00 + v01.z * w01 + v10.z * w10 + v11.z * w11;
            feat[3] = v00.w * w00 + v01.w * w01 + v10.w * w10 + v11.w * w11;
        } else {
#pragma unroll
            for (int ch = 0; ch < 4; ++ch) {
                const float* f = fm + ch * HWSZ;
                feat[ch] = f[iy0 * WW + ix0] * w00 + f[iy0 * WW + ix1] * w01 +
                           f[iy1 * WW + ix0] * w10 + f[iy1 * WW + ix1] * w11;
            }
        }

        in[j][0] = p0; in[j][1] = p1; in[j][2] = p2;
        in[j][3] = feat[0]; in[j][4] = feat[1];
        in[j][5] = feat[2]; in[j][6] = feat[3];
    }

    // ---- MLP from LDS weights, one jg-group at a time (fenced) ----
    const float4* sW1v = reinterpret_cast<const float4*>(sW + O_W1);
    const float4* sB1v = reinterpret_cast<const float4*>(sW + O_B1);
    const float4* sW2v = reinterpret_cast<const float4*>(sW + O_W2);
    const float4* sB2v = reinterpret_cast<const float4*>(sW + O_B2);
    const float4* sW3v = reinterpret_cast<const float4*>(sW + O_W3);
    const float4* sB3v = reinterpret_cast<const float4*>(sW + O_B3);
    const float4* sW4v = reinterpret_cast<const float4*>(sW + O_W4);
    const float4* sB4v = reinterpret_cast<const float4*>(sW + O_B4);
    const float4* sW5v = reinterpret_cast<const float4*>(sW + O_W5);

    float h[NP][16], g[NP][16];

    // layer 1: 7 -> 16, relu
#pragma unroll
    for (int jg = 0; jg < 4; ++jg) {
        JG_FENCE();
        float4 bb = sB1v[jg];
        float4 a[NP];
#pragma unroll
        for (int j = 0; j < NP; ++j) a[j] = bb;
#pragma unroll
        for (int k = 0; k < 7; ++k) {
            float4 w = sW1v[k * 4 + jg];
#pragma unroll
            for (int j = 0; j < NP; ++j) {
                float u = in[j][k];
                a[j].x = fmaf(u, w.x, a[j].x);
                a[j].y = fmaf(u, w.y, a[j].y);
                a[j].z = fmaf(u, w.z, a[j].z);
                a[j].w = fmaf(u, w.w, a[j].w);
            }
        }
#pragma unroll
        for (int j = 0; j < NP; ++j) {
            h[j][jg * 4 + 0] = fmaxf(a[j].x, 0.f);
            h[j][jg * 4 + 1] = fmaxf(a[j].y, 0.f);
            h[j][jg * 4 + 2] = fmaxf(a[j].z, 0.f);
            h[j][jg * 4 + 3] = fmaxf(a[j].w, 0.f);
        }
    }
    JG_FENCE();

#define LAYER16(WV, BV, src, dst)                                      \
    _Pragma("unroll")                                                  \
    for (int jg = 0; jg < 4; ++jg) {                                   \
        JG_FENCE();                                                    \
        float4 bb = (BV)[jg];                                          \
        float4 a[NP];                                                  \
        _Pragma("unroll")                                              \
        for (int j = 0; j < NP; ++j) a[j] = bb;                        \
        _Pragma("unroll")                                              \
        for (int k = 0; k < 16; ++k) {                                 \
            float4 w = (WV)[k * 4 + jg];                               \
            _Pragma("unroll")                                          \
            for (int j = 0; j < NP; ++j) {                             \
                float u = (src)[j][k];                                 \
                a[j].x = fmaf(u, w.x, a[j].x);                         \
                a[j].y = fmaf(u, w.y, a[j].y);                         \
                a[j].z = fmaf(u, w.z, a[j].z);                         \
                a[j].w = fmaf(u, w.w, a[j].w);                         \
            }                                                          \
        }                                                              \
        _Pragma("unroll")                                              \
        for (int j = 0; j < NP; ++j) {                                 \
            (dst)[j][jg * 4 + 0] = fmaxf(a[j].x, 0.f);                 \
            (dst)[j][jg * 4 + 1] = fmaxf(a[j].y, 0.f);                 \
            (dst)[j][jg * 4 + 2] = fmaxf(a[j].z, 0.f);                 \
            (dst)[j][jg * 4 + 3] = fmaxf(a[j].w, 0.f);                 \
        }                                                              \
    }

    LAYER16(sW2v, sB2v, h, g)
    JG_FENCE();
    LAYER16(sW3v, sB3v, g, h)
    JG_FENCE();
    LAYER16(sW4v, sB4v, h, g)
    JG_FENCE();
#undef LAYER16

    // layer 5: 16 -> 3 (padded to 4), no relu. 17-read window, same bound.
    float4 b5f = *reinterpret_cast<const float4*>(sW + O_B5);
    float4 a5[NP];
#pragma unroll
    for (int j = 0; j < NP; ++j) a5[j] = b5f;
#pragma unroll
    for (int k = 0; k < 16; ++k) {
        float4 w = sW5v[k];
#pragma unroll
        for (int j = 0; j < NP; ++j) {
            float u = g[j][k];
            a5[j].x = fmaf(u, w.x, a5[j].x);
            a5[j].y = fmaf(u, w.y, a5[j].y);
            a5[j].z = fmaf(u, w.z, a5[j].z);
        }
    }
    JG_FENCE();

    // ---- store (12B/lane, contiguous across the wave per j) ----
#pragma unroll
    for (int j = 0; j < NP; ++j) {
        int i = base + j * BLK;
        if (ok[j]) {
            out[3 * i]     = a5[j].x;
            out[3 * i + 1] = a5[j].y;
            out[3 * i + 2] = a5[j].z;
        }
    }
}

extern "C" void kernel_launch(void* const* d_in, const int* in_sizes, int n_in,
                              void* d_out, int out_size, void* d_ws, size_t ws_size,
                              hipStream_t stream) {
    const float* x  = (const float*)d_in[0];
    const float* fm = (const float*)d_in[1];
    const float* W1 = (const float*)d_in[2];
    const float* b1 = (const float*)d_in[3];
    const float* W2 = (const float*)d_in[4];
    const float* b2 = (const float*)d_in[5];
    const float* W3 = (const float*)d_in[6];
    const float* b3 = (const float*)d_in[7];
    const float* W4 = (const float*)d_in[8];
    const float* b4 = (const float*)d_in[9];
    const float* W5 = (const float*)d_in[10];
    const float* b5 = (const float*)d_in[11];
    float* out = (float*)d_out;

    const int n = in_sizes[0] / 3;  // 4,000,000 points
    const int grid = (n + BLK * NP - 1) / (BLK * NP);

    const size_t need = (size_t)HWSZ * 4 * sizeof(float);  // 4 MB
    if (ws_size >= need) {
        float* fmT = (float*)d_ws;
        fm_transpose<<<(HWSZ + 255) / 256, 256, 0, stream>>>(fm, fmT);
        mlp_fused<true><<<grid, BLK, 0, stream>>>(x, fmT, W1, b1, W2, b2, W3, b3,
                                                  W4, b4, W5, b5, out, n);
    } else {
        mlp_fused<false><<<grid, BLK, 0, stream>>>(x, fm, W1, b1, W2, b2, W3, b3,
                                                   W4, b4, W5, b5, out, n);
    }
}

// Round 4
// 455.158 us; speedup vs baseline: 11.0146x; 11.0146x over previous
//
#include <hip/hip_runtime.h>

#define HH 512
#define WW 512
#define HWSZ (HH * WW)
#define BLK 256

// Scheduler fence (mask 0: nothing crosses). Bounds the live range of each
// half-jg window's scalar weight loads to <=36 SGPRs. The known failure mode
// of scalar weights (previous session: "blew the 102-SGPR budget") is
// unbounded hoisting of all ~1012 weight loads; R2/R3 established that
// sched_barrier(0) at fine granularity is what bounds hoisting.
#define FENCE() __builtin_amdgcn_sched_barrier(0)

// ---------------------------------------------------------------------------
// Pre-pass: transpose featuremap (C,H,W) -> (H,W,C): one bilinear corner = one
// aligned float4 load.
// ---------------------------------------------------------------------------
__global__ void fm_transpose(const float* __restrict__ fm, float* __restrict__ fmT) {
    int i = blockIdx.x * blockDim.x + threadIdx.x;
    if (i < HWSZ) {
        float4 v;
        v.x = fm[i];
        v.y = fm[HWSZ + i];
        v.z = fm[2 * HWSZ + i];
        v.w = fm[3 * HWSZ + i];
        reinterpret_cast<float4*>(fmT)[i] = v;
    }
}

// ---------------------------------------------------------------------------
// Fused grid_sample + MLP, 1 point/thread, SCALAR (SGPR) weights.
// Weights are wave-uniform; compile-time-constant indices into __restrict__
// arg pointers scalarize to s_load (merged to s_load_dwordx4/x16) and feed
// v_fmac_f32 dst, s, v directly. This removes the 253 ds_read_b128
// broadcasts/wave (~103us/CU of LDS-pipe occupancy that serialized with the
// ~115us of VALU work in the 168us R0 kernel). No LDS, no __syncthreads.
// NP stays 1: R1-R3 proved every NP>=2 variant spills via a different
// compiler mechanism; VALU work scales with points either way.
// ---------------------------------------------------------------------------
template <bool TR>
__global__ __launch_bounds__(BLK) void mlp_fused(
    const float* __restrict__ x, const float* __restrict__ fm,
    const float* __restrict__ W1, const float* __restrict__ b1,
    const float* __restrict__ W2, const float* __restrict__ b2,
    const float* __restrict__ W3, const float* __restrict__ b3,
    const float* __restrict__ W4, const float* __restrict__ b4,
    const float* __restrict__ W5, const float* __restrict__ b5,
    float* __restrict__ out, int n)
{
    const int i = blockIdx.x * BLK + threadIdx.x;
    if (i >= n) return;

    // ---- load point coords ----
    float p0 = x[3 * i], p1 = x[3 * i + 1], p2 = x[3 * i + 2];

    // ---- bilinear sample, border clamp (identical arithmetic to reference) ----
    float gx = p0 * 2.f - 1.f;
    float gy = p1 * 2.f - 1.f;
    float fx = ((gx + 1.f) * (float)WW - 1.f) * 0.5f;
    float fy = ((gy + 1.f) * (float)HH - 1.f) * 0.5f;
    fx = fminf(fmaxf(fx, 0.f), (float)(WW - 1));
    fy = fminf(fmaxf(fy, 0.f), (float)(HH - 1));
    float x0f = floorf(fx), y0f = floorf(fy);
    float wx = fx - x0f, wy = fy - y0f;
    int ix0 = (int)x0f, iy0 = (int)y0f;
    int ix1 = min(ix0 + 1, WW - 1);
    int iy1 = min(iy0 + 1, HH - 1);
    float w00 = (1.f - wy) * (1.f - wx);
    float w01 = (1.f - wy) * wx;
    float w10 = wy * (1.f - wx);
    float w11 = wy * wx;

    float feat[4];
    if (TR) {
        const float4* fmT = reinterpret_cast<const float4*>(fm);
        float4 v00 = fmT[iy0 * WW + ix0];
        float4 v01 = fmT[iy0 * WW + ix1];
        float4 v10 = fmT[iy1 * WW + ix0];
        float4 v11 = fmT[iy1 * WW + ix1];
        feat[0] = v00.x * w00 + v01.x * w01 + v10.x * w10 + v11.x * w11;
        feat[1] = v00.y * w00 + v01.y * w01 + v10.y * w10 + v11.y * w11;
        feat[2] = v00.z * w00 + v01.z * w01 + v10.z * w10 + v11.z * w11;
        feat[3] = v00.w * w00 + v01.w * w01 + v10.w * w10 + v11.w * w11;
    } else {
#pragma unroll
        for (int ch = 0; ch < 4; ++ch) {
            const float* f = fm + ch * HWSZ;
            feat[ch] = f[iy0 * WW + ix0] * w00 + f[iy0 * WW + ix1] * w01 +
                       f[iy1 * WW + ix0] * w10 + f[iy1 * WW + ix1] * w11;
        }
    }

    float in[7] = {p0, p1, p2, feat[0], feat[1], feat[2], feat[3]};
    float h[16], g[16];

    FENCE();
    // ---- layer 1: 7 -> 16, relu. Window: 28 weights + 4 bias = 32 SGPRs. ----
#pragma unroll
    for (int jg = 0; jg < 4; ++jg) {
        float a0 = b1[jg * 4 + 0], a1 = b1[jg * 4 + 1];
        float a2 = b1[jg * 4 + 2], a3 = b1[jg * 4 + 3];
#pragma unroll
        for (int k = 0; k < 7; ++k) {
            float u = in[k];
            a0 = fmaf(u, W1[k * 16 + jg * 4 + 0], a0);
            a1 = fmaf(u, W1[k * 16 + jg * 4 + 1], a1);
            a2 = fmaf(u, W1[k * 16 + jg * 4 + 2], a2);
            a3 = fmaf(u, W1[k * 16 + jg * 4 + 3], a3);
        }
        h[jg * 4 + 0] = fmaxf(a0, 0.f);
        h[jg * 4 + 1] = fmaxf(a1, 0.f);
        h[jg * 4 + 2] = fmaxf(a2, 0.f);
        h[jg * 4 + 3] = fmaxf(a3, 0.f);
        FENCE();
    }

    // ---- 16->16 layers, relu. Each fenced window: 32 weights (+4 bias). ----
#define LAYER16(Wp, bp, src, dst)                                        \
    _Pragma("unroll")                                                    \
    for (int jg = 0; jg < 4; ++jg) {                                     \
        float a0 = (bp)[jg * 4 + 0], a1 = (bp)[jg * 4 + 1];              \
        float a2 = (bp)[jg * 4 + 2], a3 = (bp)[jg * 4 + 3];              \
        _Pragma("unroll")                                                \
        for (int k = 0; k < 8; ++k) {                                    \
            float u = (src)[k];                                          \
            a0 = fmaf(u, (Wp)[k * 16 + jg * 4 + 0], a0);                 \
            a1 = fmaf(u, (Wp)[k * 16 + jg * 4 + 1], a1);                 \
            a2 = fmaf(u, (Wp)[k * 16 + jg * 4 + 2], a2);                 \
            a3 = fmaf(u, (Wp)[k * 16 + jg * 4 + 3], a3);                 \
        }                                                                \
        FENCE();                                                         \
        _Pragma("unroll")                                                \
        for (int k = 8; k < 16; ++k) {                                   \
            float u = (src)[k];                                          \
            a0 = fmaf(u, (Wp)[k * 16 + jg * 4 + 0], a0);                 \
            a1 = fmaf(u, (Wp)[k * 16 + jg * 4 + 1], a1);                 \
            a2 = fmaf(u, (Wp)[k * 16 + jg * 4 + 2], a2);                 \
            a3 = fmaf(u, (Wp)[k * 16 + jg * 4 + 3], a3);                 \
        }                                                                \
        (dst)[jg * 4 + 0] = fmaxf(a0, 0.f);                              \
        (dst)[jg * 4 + 1] = fmaxf(a1, 0.f);                              \
        (dst)[jg * 4 + 2] = fmaxf(a2, 0.f);                              \
        (dst)[jg * 4 + 3] = fmaxf(a3, 0.f);                              \
        FENCE();                                                         \
    }

    LAYER16(W2, b2, h, g)
    LAYER16(W3, b3, g, h)
    LAYER16(W4, b4, h, g)
#undef LAYER16

    // ---- layer 5: 16 -> 3, no relu. Two windows of 24 weights. ----
    float a50 = b5[0], a51 = b5[1], a52 = b5[2];
#pragma unroll
    for (int k = 0; k < 8; ++k) {
        float u = g[k];
        a50 = fmaf(u, W5[k * 3 + 0], a50);
        a51 = fmaf(u, W5[k * 3 + 1], a51);
        a52 = fmaf(u, W5[k * 3 + 2], a52);
    }
    FENCE();
#pragma unroll
    for (int k = 8; k < 16; ++k) {
        float u = g[k];
        a50 = fmaf(u, W5[k * 3 + 0], a50);
        a51 = fmaf(u, W5[k * 3 + 1], a51);
        a52 = fmaf(u, W5[k * 3 + 2], a52);
    }
    FENCE();

    // ---- store (12B/lane, contiguous across the wave) ----
    out[3 * i]     = a50;
    out[3 * i + 1] = a51;
    out[3 * i + 2] = a52;
}

extern "C" void kernel_launch(void* const* d_in, const int* in_sizes, int n_in,
                              void* d_out, int out_size, void* d_ws, size_t ws_size,
                              hipStream_t stream) {
    const float* x  = (const float*)d_in[0];
    const float* fm = (const float*)d_in[1];
    const float* W1 = (const float*)d_in[2];
    const float* b1 = (const float*)d_in[3];
    const float* W2 = (const float*)d_in[4];
    const float* b2 = (const float*)d_in[5];
    const float* W3 = (const float*)d_in[6];
    const float* b3 = (const float*)d_in[7];
    const float* W4 = (const float*)d_in[8];
    const float* b4 = (const float*)d_in[9];
    const float* W5 = (const float*)d_in[10];
    const float* b5 = (const float*)d_in[11];
    float* out = (float*)d_out;

    const int n = in_sizes[0] / 3;  // 4,000,000 points
    const int grid = (n + BLK - 1) / BLK;

    const size_t need = (size_t)HWSZ * 4 * sizeof(float);  // 4 MB
    if (ws_size >= need) {
        float* fmT = (float*)d_ws;
        fm_transpose<<<(HWSZ + 255) / 256, 256, 0, stream>>>(fm, fmT);
        mlp_fused<true><<<grid, BLK, 0, stream>>>(x, fmT, W1, b1, W2, b2, W3, b3,
                                                  W4, b4, W5, b5, out, n);
    } else {
        mlp_fused<false><<<grid, BLK, 0, stream>>>(x, fm, W1, b1, W2, b2, W3, b3,
                                                   W4, b4, W5, b5, out, n);
    }
}